// Round 2
// baseline (427.203 us; speedup 1.0000x reference)
//
#include <hip/hip_runtime.h>

// Problem constants
#define H_DIM 2048
#define E_DIM 8
#define T_DIM 2048
#define F_DIM 4096                 // INTER*2
#define NBLK  1024                 // 8 e * 128 h-chunks; exactly 4 blocks/CU, uniform work
#define HCHUNK 16                  // h-columns per block (one 64B line per t)

typedef float f32x4 __attribute__((ext_vector_type(4)));

// One fused kernel, zero workspace:
//   result = sum_{e,h} A[e,h] * B[e,h],  A = sum_t mask[e,t]*hidden[t,h],  B = sum_f W[e,h,f]
// Block b owns expert e = b>>7 and h-range [h0, h0+16).
// KEY CHANGE vs prev round: the A-accumulation (L2/L3-resident hidden reads) is
// interleaved INTO the W-streaming loop instead of running serially before it.
// A is only needed at the final dot, so the merged loop is pure memory
// throughput; A-load latency hides under the HBM W stream. Cross-wave A
// reduction happens in the epilogue.
__global__ __launch_bounds__(256, 4) void moe_dot(
    const float* __restrict__ hidden,   // [T, H]
    const float* __restrict__ W,        // [E, H, F]
    const float* __restrict__ mask,     // [E, T]
    float* __restrict__ out) {
  const int tid = threadIdx.x;
  const int bid = blockIdx.x;
  const int e   = bid >> 7;                 // 0..7
  const int h0  = (bid & 127) * HCHUNK;     // 0..2032

  __shared__ float m_lds[T_DIM];            // 8 KB: mask row for this expert
  __shared__ f32x4 redA[4][4];              // cross-wave A reduction
  __shared__ float A_val[HCHUNK];           // A[e, h0+i]
  __shared__ float wsum[4];

  // ---- stage mask[e, :] into LDS (coalesced f32x4) ----
  {
    const f32x4* m4 = (const f32x4*)(mask + (size_t)e * T_DIM);
    f32x4* l4 = (f32x4*)m_lds;
    l4[tid]       = m4[tid];
    l4[tid + 256] = m4[tid + 256];
  }
  __syncthreads();

  // lane roles
  const int hq   = tid & 3;                 // A-phase: h-quad within 64B line
  const int ttg  = tid >> 2;                // A-phase: t-group 0..63 (waves partition t)
  const int wave = tid >> 6;
  const int lane = tid & 63;
  const int rl   = wave << 2;               // B-phase: 4 contiguous rows per wave

  const float* hp = hidden + h0 + (hq << 2);
  const f32x4* rp = (const f32x4*)(W + ((size_t)e * H_DIM + h0 + rl) * F_DIM);

  f32x4 accA = (f32x4)0.f;
  f32x4 a0 = (f32x4)0.f, a1 = (f32x4)0.f, a2 = (f32x4)0.f, a3 = (f32x4)0.f;

  // ---- merged stream: 16 B-iters (256KB W, HBM) + 32 A-iters folded in ----
  #pragma unroll
  for (int i = 0; i < 16; ++i) {
    int idx = lane + (i << 6);
    a0 += __builtin_nontemporal_load(&rp[idx]);          // W streamed once:
    a1 += __builtin_nontemporal_load(&rp[idx + 1024]);   // nt keeps hidden in L2/L3
    a2 += __builtin_nontemporal_load(&rp[idx + 2048]);
    a3 += __builtin_nontemporal_load(&rp[idx + 3072]);
    if (i < 8) {
      #pragma unroll
      for (int j = 0; j < 4; ++j) {
        int t = ttg + ((i * 4 + j) << 6);
        f32x4 hv = *(const f32x4*)(hp + (size_t)t * H_DIM);
        accA += hv * m_lds[t];               // 4-lane-uniform LDS broadcast
      }
    }
  }

  // ---- epilogue: cross-wave A reduction (over ttg within wave, then waves) ----
  #pragma unroll
  for (int off = 4; off <= 32; off <<= 1) {
    accA.x += __shfl_down(accA.x, off, 64);
    accA.y += __shfl_down(accA.y, off, 64);
    accA.z += __shfl_down(accA.z, off, 64);
    accA.w += __shfl_down(accA.w, off, 64);
  }
  if (lane < 4) redA[wave][lane] = accA;
  __syncthreads();
  if (tid < 4)
    ((f32x4*)A_val)[tid] = (redA[0][tid] + redA[1][tid]) + (redA[2][tid] + redA[3][tid]);
  __syncthreads();

  // ---- final dot: per-row W sums x A, then block reduce + one atomic ----
  float dot = ((a0.x + a0.y) + (a0.z + a0.w)) * A_val[rl]
            + ((a1.x + a1.y) + (a1.z + a1.w)) * A_val[rl + 1]
            + ((a2.x + a2.y) + (a2.z + a2.w)) * A_val[rl + 2]
            + ((a3.x + a3.y) + (a3.z + a3.w)) * A_val[rl + 3];

  #pragma unroll
  for (int off = 32; off > 0; off >>= 1)
    dot += __shfl_down(dot, off, 64);
  if (lane == 0) wsum[wave] = dot;
  __syncthreads();
  if (tid == 0)
    atomicAdd(out, (wsum[0] + wsum[1]) + (wsum[2] + wsum[3]));
}

extern "C" void kernel_launch(void* const* d_in, const int* in_sizes, int n_in,
                              void* d_out, int out_size, void* d_ws, size_t ws_size,
                              hipStream_t stream) {
  const float* hidden = (const float*)d_in[0];  // [1,1,T,H] fp32
  const float* W      = (const float*)d_in[1];  // [1,E,H,2*INTER] fp32
  const float* mask   = (const float*)d_in[2];  // [1,E,T,1] fp32
  float* out = (float*)d_out;

  hipMemsetAsync(d_out, 0, sizeof(float), stream);   // graph-capturable memset node
  moe_dot<<<NBLK, 256, 0, stream>>>(hidden, W, mask, out);
}

// Round 3
// 387.751 us; speedup vs baseline: 1.1017x; 1.1017x over previous
//
#include <hip/hip_runtime.h>

// Problem constants
#define H_DIM 2048
#define E_DIM 8
#define T_DIM 2048
#define F_DIM 4096                 // INTER*2
#define NBLK  1024                 // 8 e * 128 h-chunks; exactly 4 blocks/CU, uniform work
#define HCHUNK 16                  // h-columns per block (one 64B line per t)

typedef float f32x4 __attribute__((ext_vector_type(4)));

// One fused kernel, zero workspace:
//   result = sum_{e,h} A[e,h] * B[e,h],  A = sum_t mask[e,t]*hidden[t,h],  B = sum_f W[e,h,f]
// Block b owns expert e = b>>7 and h-range [h0, h0+16).
// R3: gentle A/B interleave. R2's full-unroll merge spilled (128-VGPR cap from
// launch_bounds) and used nt loads; both reverted. Loops stay ROLLED
// (#pragma unroll 2) so ~8 loads/wave in flight, no spills; A-iters ride in the
// first half of the W stream so their L2/L3 latency hides under HBM traffic.
__global__ __launch_bounds__(256, 4) void moe_dot(
    const float* __restrict__ hidden,   // [T, H]
    const float* __restrict__ W,        // [E, H, F]
    const float* __restrict__ mask,     // [E, T]
    float* __restrict__ out) {
  const int tid = threadIdx.x;
  const int bid = blockIdx.x;
  const int e   = bid >> 7;                 // 0..7
  const int h0  = (bid & 127) * HCHUNK;     // 0..2032

  __shared__ float m_lds[T_DIM];            // 8 KB: mask row for this expert
  __shared__ f32x4 redA[4][4];              // cross-wave A reduction
  __shared__ float A_val[HCHUNK];           // A[e, h0+i]
  __shared__ float wsum[4];

  // ---- stage mask[e, :] into LDS (coalesced f32x4) ----
  {
    const f32x4* m4 = (const f32x4*)(mask + (size_t)e * T_DIM);
    f32x4* l4 = (f32x4*)m_lds;
    l4[tid]       = m4[tid];
    l4[tid + 256] = m4[tid + 256];
  }
  __syncthreads();

  // lane roles
  const int hq   = tid & 3;                 // A: h-quad within the block's 64B line
  const int ttg  = tid >> 2;                // A: t-group 0..63
  const int wave = tid >> 6;
  const int lane = tid & 63;
  const int rl   = wave << 2;               // B: 4 contiguous rows per wave

  const float* hp = hidden + h0 + (hq << 2);
  const f32x4* rp = (const f32x4*)(W + ((size_t)e * H_DIM + h0 + rl) * F_DIM);

  f32x4 accA = (f32x4)0.f;
  f32x4 a0 = (f32x4)0.f, a1 = (f32x4)0.f, a2 = (f32x4)0.f, a3 = (f32x4)0.f;

  // ---- first half: 8 B-iters with 4 A-iters folded into each (rolled) ----
  #pragma unroll 2
  for (int i = 0; i < 8; ++i) {
    int idx = lane + (i << 6);
    f32x4 w0 = rp[idx];
    f32x4 w1 = rp[idx + 1024];
    f32x4 w2 = rp[idx + 2048];
    f32x4 w3 = rp[idx + 3072];
    #pragma unroll
    for (int j = 0; j < 4; ++j) {
      int t = ttg + ((i * 4 + j) << 6);
      f32x4 hv = *(const f32x4*)(hp + (size_t)t * H_DIM);
      accA += hv * m_lds[t];               // 4-lane-uniform LDS broadcast, conflict-free
    }
    a0 += w0; a1 += w1; a2 += w2; a3 += w3;
  }
  // ---- second half: pure W stream ----
  #pragma unroll 2
  for (int i = 8; i < 16; ++i) {
    int idx = lane + (i << 6);
    a0 += rp[idx];
    a1 += rp[idx + 1024];
    a2 += rp[idx + 2048];
    a3 += rp[idx + 3072];
  }

  // ---- epilogue: cross-wave A reduction (over ttg within wave, then waves) ----
  #pragma unroll
  for (int off = 4; off <= 32; off <<= 1) {
    accA.x += __shfl_down(accA.x, off, 64);
    accA.y += __shfl_down(accA.y, off, 64);
    accA.z += __shfl_down(accA.z, off, 64);
    accA.w += __shfl_down(accA.w, off, 64);
  }
  if (lane < 4) redA[wave][lane] = accA;
  __syncthreads();
  if (tid < 4)
    ((f32x4*)A_val)[tid] = (redA[0][tid] + redA[1][tid]) + (redA[2][tid] + redA[3][tid]);
  __syncthreads();

  // ---- final dot: per-row W sums x A, then block reduce + one atomic ----
  float dot = ((a0.x + a0.y) + (a0.z + a0.w)) * A_val[rl]
            + ((a1.x + a1.y) + (a1.z + a1.w)) * A_val[rl + 1]
            + ((a2.x + a2.y) + (a2.z + a2.w)) * A_val[rl + 2]
            + ((a3.x + a3.y) + (a3.z + a3.w)) * A_val[rl + 3];

  #pragma unroll
  for (int off = 32; off > 0; off >>= 1)
    dot += __shfl_down(dot, off, 64);
  if (lane == 0) wsum[wave] = dot;
  __syncthreads();
  if (tid == 0)
    atomicAdd(out, (wsum[0] + wsum[1]) + (wsum[2] + wsum[3]));
}

extern "C" void kernel_launch(void* const* d_in, const int* in_sizes, int n_in,
                              void* d_out, int out_size, void* d_ws, size_t ws_size,
                              hipStream_t stream) {
  const float* hidden = (const float*)d_in[0];  // [1,1,T,H] fp32
  const float* W      = (const float*)d_in[1];  // [1,E,H,2*INTER] fp32
  const float* mask   = (const float*)d_in[2];  // [1,E,T,1] fp32
  float* out = (float*)d_out;

  hipMemsetAsync(d_out, 0, sizeof(float), stream);   // graph-capturable memset node
  moe_dot<<<NBLK, 256, 0, stream>>>(hidden, W, mask, out);
}

// Round 4
// 380.053 us; speedup vs baseline: 1.1241x; 1.0203x over previous
//
#include <hip/hip_runtime.h>

// Problem constants
#define H_DIM 2048
#define E_DIM 8
#define T_DIM 2048
#define F_DIM 4096                 // INTER*2
#define NBLK  1024                 // 8 e * 128 h-chunks; exactly 4 blocks/CU, uniform
#define HCHUNK 16                  // h-columns per block

typedef float f32x4 __attribute__((ext_vector_type(4)));

// result = sum_{e,h} A[e,h]*B[e,h];  A = sum_t mask[e,t]*hidden[t,h];  B = sum_f W[e,h,f]
// R4: WAVE SPECIALIZATION. R1 (best, 382.5) ran A serially before W (~5us exposed);
// R2/R3 interleaving failed (spill / L2-thrash of the hidden burst). Here one
// producer wave per block computes all 16 A values (~3us, L2-resident: the 8
// e-sibling blocks share the slice on the same XCD) while the other 3 waves
// start streaming W at cycle 0 -- no entry barrier at all. Producer also takes
// 1 of 16 W rows (1+5+5+5). Producer wave id rotates with bid&3 to spread
// A-work across SIMDs. Only 2 barriers, both in the epilogue.
__global__ __launch_bounds__(256, 4) void moe_dot(
    const float* __restrict__ hidden,   // [T, H]
    const float* __restrict__ W,        // [E, H, F]
    const float* __restrict__ mask,     // [E, T]
    float* __restrict__ out) {
  const int tid  = threadIdx.x;
  const int bid  = blockIdx.x;
  const int e    = bid >> 7;                // 0..7
  const int h0   = (bid & 127) * HCHUNK;    // 0..2032
  const int wave = tid >> 6;
  const int lane = tid & 63;

  __shared__ float m_lds[T_DIM];            // 8 KB: mask row (producer-only)
  __shared__ float A_val[HCHUNK];           // A[e, h0+i]
  __shared__ float wsum[4];

  const size_t wbase = ((size_t)e * H_DIM + h0) * F_DIM;
  const int awave = bid & 3;                // rotate producer across SIMDs
  const bool producer = (wave == awave);

  float sdot[5];
  int r0 = 0;

  if (producer) {
    // ---- stage mask[e,:] (8 KB, producer-private, no barrier needed) ----
    const f32x4* m4 = (const f32x4*)(mask + (size_t)e * T_DIM);
    f32x4* l4 = (f32x4*)m_lds;
    #pragma unroll
    for (int i = 0; i < 8; ++i) l4[lane + (i << 6)] = m4[lane + (i << 6)];

    // ---- A[h0+hh] = sum_t mask[t]*hidden[t,hh]: lane=(ttg,hq), 128 iters ----
    const int hq  = lane & 3;
    const int ttg = lane >> 2;              // 0..15
    const float* hp = hidden + h0 + (hq << 2);
    f32x4 accA = (f32x4)0.f;
    #pragma unroll 8
    for (int k = 0; k < 128; ++k) {
      int t = ttg + (k << 4);
      accA += *(const f32x4*)(hp + (size_t)t * H_DIM) * m_lds[t];
    }
    #pragma unroll
    for (int off = 4; off <= 32; off <<= 1) {
      accA.x += __shfl_down(accA.x, off, 64);
      accA.y += __shfl_down(accA.y, off, 64);
      accA.z += __shfl_down(accA.z, off, 64);
      accA.w += __shfl_down(accA.w, off, 64);
    }
    if (lane < 4) ((f32x4*)A_val)[lane] = accA;   // lanes 0-3 hold h-quads 0-3

    // ---- producer's W share: row 15 ----
    const f32x4* rp = (const f32x4*)(W + wbase + (size_t)15 * F_DIM);
    f32x4 a = (f32x4)0.f;
    #pragma unroll 4
    for (int i = 0; i < 16; ++i) a += rp[lane + (i << 6)];
    float s = (a.x + a.y) + (a.z + a.w);
    #pragma unroll
    for (int off = 32; off > 0; off >>= 1) s += __shfl_down(s, off, 64);
    if (lane == 0) wsum[wave] = s * A_val[15];    // A_val is wave-local here
  } else {
    // ---- streamer: 5 contiguous W rows, start at cycle 0 ----
    const int sw = wave - (wave > awave ? 1 : 0); // 0..2
    r0 = sw * 5;
    const f32x4* rp = (const f32x4*)(W + wbase + (size_t)r0 * F_DIM);
    f32x4 a0 = (f32x4)0.f, a1 = (f32x4)0.f, a2 = (f32x4)0.f,
          a3 = (f32x4)0.f, a4 = (f32x4)0.f;
    #pragma unroll 2
    for (int i = 0; i < 16; ++i) {
      int idx = lane + (i << 6);
      a0 += rp[idx];
      a1 += rp[idx + 1024];
      a2 += rp[idx + 2048];
      a3 += rp[idx + 3072];
      a4 += rp[idx + 4096];
    }
    sdot[0] = (a0.x + a0.y) + (a0.z + a0.w);
    sdot[1] = (a1.x + a1.y) + (a1.z + a1.w);
    sdot[2] = (a2.x + a2.y) + (a2.z + a2.w);
    sdot[3] = (a3.x + a3.y) + (a3.z + a3.w);
    sdot[4] = (a4.x + a4.y) + (a4.z + a4.w);
    #pragma unroll
    for (int off = 32; off > 0; off >>= 1) {      // 5 ILP'd shuffle chains
      sdot[0] += __shfl_down(sdot[0], off, 64);
      sdot[1] += __shfl_down(sdot[1], off, 64);
      sdot[2] += __shfl_down(sdot[2], off, 64);
      sdot[3] += __shfl_down(sdot[3], off, 64);
      sdot[4] += __shfl_down(sdot[4], off, 64);
    }
  }

  __syncthreads();                                // A_val + wsum[awave] visible
  if (!producer && lane == 0)
    wsum[wave] = sdot[0] * A_val[r0]     + sdot[1] * A_val[r0 + 1]
               + sdot[2] * A_val[r0 + 2] + sdot[3] * A_val[r0 + 3]
               + sdot[4] * A_val[r0 + 4];
  __syncthreads();
  if (tid == 0)
    atomicAdd(out, (wsum[0] + wsum[1]) + (wsum[2] + wsum[3]));
}

extern "C" void kernel_launch(void* const* d_in, const int* in_sizes, int n_in,
                              void* d_out, int out_size, void* d_ws, size_t ws_size,
                              hipStream_t stream) {
  const float* hidden = (const float*)d_in[0];  // [1,1,T,H] fp32
  const float* W      = (const float*)d_in[1];  // [1,E,H,2*INTER] fp32
  const float* mask   = (const float*)d_in[2];  // [1,E,T,1] fp32
  float* out = (float*)d_out;

  hipMemsetAsync(d_out, 0, sizeof(float), stream);   // graph-capturable memset node
  moe_dot<<<NBLK, 256, 0, stream>>>(hidden, W, mask, out);
}

// Round 5
// 378.484 us; speedup vs baseline: 1.1287x; 1.0041x over previous
//
#include <hip/hip_runtime.h>

// Problem constants
#define H_DIM 2048
#define E_DIM 8
#define T_DIM 2048
#define F_DIM 4096                 // INTER*2
#define NBLK  1024                 // 8 e * 128 h-chunks; exactly 4 blocks/CU, uniform
#define HCHUNK 16                  // h-columns per block

typedef float f32x4 __attribute__((ext_vector_type(4)));

// result = sum_{e,h} A[e,h]*B[e,h];  A = sum_t mask[e,t]*hidden[t,h];  B = sum_f W[e,h,f]
// R5: BALANCED wave specialization. R4's 1+5+5+5 split left producers idle for
// ~70% of the stream (A costs ~0.3 row-equivalents, not 5). Now ALL waves
// stream 4 rows; the producer wave (rotating, bid&3) computes A first and lags
// by ~3us -- a small tail instead of a 35us idle. Stream loop unroll 4 deepens
// per-wave MLP (~16 outstanding loads, ~100 VGPR, no spill at the 128 cap).
__global__ __launch_bounds__(256, 4) void moe_dot(
    const float* __restrict__ hidden,   // [T, H]
    const float* __restrict__ W,        // [E, H, F]
    const float* __restrict__ mask,     // [E, T]
    float* __restrict__ out) {
  const int tid  = threadIdx.x;
  const int bid  = blockIdx.x;
  const int e    = bid >> 7;                // 0..7
  const int h0   = (bid & 127) * HCHUNK;    // 0..2032
  const int wave = tid >> 6;
  const int lane = tid & 63;

  __shared__ float m_lds[T_DIM];            // 8 KB: mask row (producer-only)
  __shared__ float A_val[HCHUNK];           // A[e, h0+i]
  __shared__ float wsum[4];

  const size_t wbase = ((size_t)e * H_DIM + h0) * F_DIM;
  const int awave = bid & 3;                // rotate producer across SIMDs

  if (wave == awave) {
    // ---- producer: stage mask[e,:] (8 KB, wave-private, no barrier) ----
    const f32x4* m4 = (const f32x4*)(mask + (size_t)e * T_DIM);
    f32x4* l4 = (f32x4*)m_lds;
    #pragma unroll
    for (int i = 0; i < 8; ++i) l4[lane + (i << 6)] = m4[lane + (i << 6)];

    // ---- A[h0+hh] = sum_t mask[t]*hidden[t,hh]: lane=(ttg,hq), 128 iters ----
    const int hq  = lane & 3;
    const int ttg = lane >> 2;              // 0..15
    const float* hp = hidden + h0 + (hq << 2);
    f32x4 accA = (f32x4)0.f;
    #pragma unroll 8
    for (int k = 0; k < 128; ++k) {
      int t = ttg + (k << 4);
      accA += *(const f32x4*)(hp + (size_t)t * H_DIM) * m_lds[t];
    }
    #pragma unroll
    for (int off = 4; off <= 32; off <<= 1) {
      accA.x += __shfl_down(accA.x, off, 64);
      accA.y += __shfl_down(accA.y, off, 64);
      accA.z += __shfl_down(accA.z, off, 64);
      accA.w += __shfl_down(accA.w, off, 64);
    }
    if (lane < 4) ((f32x4*)A_val)[lane] = accA;   // lanes 0-3 hold h-quads 0-3
  }

  // ---- all 4 waves stream 4 contiguous W rows each (64 KB/wave) ----
  const int r0 = wave << 2;
  const f32x4* rp = (const f32x4*)(W + wbase + (size_t)r0 * F_DIM);
  f32x4 a0 = (f32x4)0.f, a1 = (f32x4)0.f, a2 = (f32x4)0.f, a3 = (f32x4)0.f;
  #pragma unroll 4
  for (int i = 0; i < 16; ++i) {
    int idx = lane + (i << 6);
    a0 += rp[idx];
    a1 += rp[idx + 1024];                   // +1 row (4096 floats)
    a2 += rp[idx + 2048];
    a3 += rp[idx + 3072];
  }
  float s0 = (a0.x + a0.y) + (a0.z + a0.w);
  float s1 = (a1.x + a1.y) + (a1.z + a1.w);
  float s2 = (a2.x + a2.y) + (a2.z + a2.w);
  float s3 = (a3.x + a3.y) + (a3.z + a3.w);
  #pragma unroll
  for (int off = 32; off > 0; off >>= 1) {  // 4 ILP'd shuffle chains
    s0 += __shfl_down(s0, off, 64);
    s1 += __shfl_down(s1, off, 64);
    s2 += __shfl_down(s2, off, 64);
    s3 += __shfl_down(s3, off, 64);
  }

  __syncthreads();                          // A_val visible to all waves
  if (lane == 0)
    wsum[wave] = s0 * A_val[r0]     + s1 * A_val[r0 + 1]
               + s2 * A_val[r0 + 2] + s3 * A_val[r0 + 3];
  __syncthreads();
  if (tid == 0)
    atomicAdd(out, (wsum[0] + wsum[1]) + (wsum[2] + wsum[3]));
}

extern "C" void kernel_launch(void* const* d_in, const int* in_sizes, int n_in,
                              void* d_out, int out_size, void* d_ws, size_t ws_size,
                              hipStream_t stream) {
  const float* hidden = (const float*)d_in[0];  // [1,1,T,H] fp32
  const float* W      = (const float*)d_in[1];  // [1,E,H,2*INTER] fp32
  const float* mask   = (const float*)d_in[2];  // [1,E,T,1] fp32
  float* out = (float*)d_out;

  hipMemsetAsync(d_out, 0, sizeof(float), stream);   // graph-capturable memset node
  moe_dot<<<NBLK, 256, 0, stream>>>(hidden, W, mask, out);
}